// Round 2
// baseline (378.249 us; speedup 1.0000x reference)
//
#include <hip/hip_runtime.h>
#include <stdint.h>

#define V      768
#define FINC   32
#define FOUTC  32
#define XYZ    512
#define NB     2
#define ROWP   40      // padded LDS row stride in ushorts (80 B, 16B-aligned)
#define MAXDEG 32

typedef unsigned short u16;
typedef unsigned int   u32;
typedef short bf16x8 __attribute__((ext_vector_type(8)));
typedef float f32x4  __attribute__((ext_vector_type(4)));
typedef float f32x2  __attribute__((ext_vector_type(2)));

__device__ __forceinline__ u16 f2bf(float f) {
  u32 u = __float_as_uint(f);
  u32 r = u + 0x7fffu + ((u >> 16) & 1u);   // RNE
  return (u16)(r >> 16);
}
__device__ __forceinline__ float bflo(u32 w) { return __uint_as_float(w << 16); }
__device__ __forceinline__ float bfhi(u32 w) { return __uint_as_float(w & 0xffff0000u); }
__device__ __forceinline__ u32 pack2(f32x2 v) {
  return (u32)f2bf(v[0]) | ((u32)f2bf(v[1]) << 16);
}

// ---------- kernel 1: x [B,Fin,V,XYZ] f32 -> xT [B,XYZ,V,Fin] bf16 ----------
__global__ __launch_bounds__(512) void transpose_x(const float* __restrict__ x,
                                                   u16* __restrict__ xT) {
  int g = blockIdx.x;            // b*V + v
  int b = g / V, v = g - b * V;
  int t = threadIdx.x;           // xyz
  float vals[FINC];
  const float* src = x + ((size_t)(b * FINC) * V + v) * XYZ + t;
#pragma unroll
  for (int f = 0; f < FINC; ++f) vals[f] = src[(size_t)f * V * XYZ];   // coalesced over t
  u32 pw[16];
#pragma unroll
  for (int p = 0; p < 16; ++p)
    pw[p] = (u32)f2bf(vals[2 * p]) | ((u32)f2bf(vals[2 * p + 1]) << 16);
  uint4* dst = (uint4*)(xT + ((size_t)(b * XYZ + t) * V + v) * FINC);  // 64B per thread
#pragma unroll
  for (int q = 0; q < 4; ++q)
    dst[q] = make_uint4(pw[4 * q], pw[4 * q + 1], pw[4 * q + 2], pw[4 * q + 3]);
}

// ---------- kernel 2: deterministic ELL build, interleaved (col,val) ----------
__global__ __launch_bounds__(64) void build_ell(const int* __restrict__ rows,
                                                const int* __restrict__ cols,
                                                const float* __restrict__ vals,
                                                int nnz,
                                                int2* __restrict__ epair,
                                                int* __restrict__ deg) {
  int v = blockIdx.x;
  int lane = threadIdx.x;
  int cnt = 0;
  for (int base = 0; base < nnz; base += 64) {
    int i = base + lane;
    bool m = (i < nnz) && (rows[i] == v);
    unsigned long long mask = __ballot(m);
    if (m) {
      int pos = cnt + __popcll(mask & ((1ull << lane) - 1ull));
      if (pos < MAXDEG)
        epair[v * MAXDEG + pos] = make_int2(cols[i], __float_as_int(vals[i]));
    }
    cnt += __popcll(mask);
  }
  if (lane == 0) deg[v] = cnt < MAXDEG ? cnt : MAXDEG;
}

// ---------- kernel 3: fused recursion + MFMA GEMM, single LDS buffer ----------
__global__ __launch_bounds__(768) void cheb_main(
    const u16* __restrict__ xT, const int2* __restrict__ epair,
    const int* __restrict__ deg, const float* __restrict__ weight,
    const float* __restrict__ bias, float* __restrict__ out) {
  __shared__ __align__(16) u16 CUR[V * ROWP];   // 61440 B -> 2 blocks/CU

  int g = blockIdx.x;
  // XCD swizzle: XCD x handles xyz in [x*64, x*64+64) -> L2 write-merge
  int xcd = g & 7, slot = g >> 3;
  int xyz = xcd * 64 + (slot & 63);
  int b = slot >> 6;
  int tid = threadIdx.x;
  int lane = tid & 63;
  int w = tid >> 6;               // wave 0..11
  int l15 = lane & 15, l4 = lane >> 4;

  // ---- preload all weight B-fragments (5 k x 2 n) + bias into registers
  bf16x8 bfr[5][2];
#pragma unroll
  for (int k = 0; k < 5; ++k)
#pragma unroll
    for (int n = 0; n < 2; ++n)
#pragma unroll
      for (int j = 0; j < 8; ++j) {
        float wv = weight[(size_t)(k * FINC + l4 * 8 + j) * FOUTC + n * 16 + l15];
        bfr[k][n][j] = (short)f2bf(wv);
      }
  float bsv[2] = {bias[l15], bias[16 + l15]};

  // ---- load slice row v into LDS and keep packed copy in regs
  u32 curpk[16], prevpk[16];
  {
    const uint4* src = (const uint4*)(xT + (size_t)(b * XYZ + xyz) * V * FINC) + tid * 4;
    uint4* dst = (uint4*)(CUR + tid * ROWP);
#pragma unroll
    for (int j = 0; j < 4; ++j) {
      uint4 q = src[j];
      dst[j] = q;
      curpk[4 * j] = q.x; curpk[4 * j + 1] = q.y;
      curpk[4 * j + 2] = q.z; curpk[4 * j + 3] = q.w;
    }
  }
  __syncthreads();

  f32x4 acc[4][2];
#pragma unroll
  for (int a = 0; a < 4; ++a)
#pragma unroll
    for (int n = 0; n < 2; ++n) acc[a][n] = (f32x4){0.f, 0.f, 0.f, 0.f};

  // out[v,fout] += sum_fin CUR[v,fin] * W[k,fin,fout]
  auto gemm_acc = [&](int k) {
#pragma unroll
    for (int a = 0; a < 4; ++a) {
      int row = (w * 4 + a) * 16 + l15;
      bf16x8 af = *(const bf16x8*)(CUR + row * ROWP + l4 * 8);
#pragma unroll
      for (int n = 0; n < 2; ++n)
        acc[a][n] = __builtin_amdgcn_mfma_f32_16x16x32_bf16(af, bfr[k][n], acc[a][n], 0, 0, 0);
    }
  };

  // fa2 = (L * CUR)[v, :]  (thread v gathers its neighbors from LDS)
  f32x2 fa2[16];
  auto gather = [&]() {
    int v = tid;
    int dg = deg[v];
#pragma unroll
    for (int j = 0; j < 16; ++j) fa2[j] = (f32x2){0.f, 0.f};
    const int2* pp = epair + v * MAXDEG;
    for (int e = 0; e < dg; ++e) {
      int2 pe = pp[e];
      int   c  = pe.x;
      float fv = __int_as_float(pe.y);
      f32x2 fv2 = {fv, fv};
      const uint4* sp = (const uint4*)(CUR + c * ROWP);
#pragma unroll
      for (int j = 0; j < 4; ++j) {
        uint4 q = sp[j];
        u32 wq[4] = {q.x, q.y, q.z, q.w};
#pragma unroll
        for (int p = 0; p < 4; ++p) {
          f32x2 s = {bflo(wq[p]), bfhi(wq[p])};
          fa2[j * 4 + p] += fv2 * s;
        }
      }
    }
  };

  auto store_cur = [&]() {
    uint4* dp = (uint4*)(CUR + tid * ROWP);
#pragma unroll
    for (int j = 0; j < 4; ++j)
      dp[j] = make_uint4(curpk[4 * j], curpk[4 * j + 1], curpk[4 * j + 2], curpk[4 * j + 3]);
  };

  // ---- phase 0: T0 resident
  gemm_acc(0);
  gather();                       // L*T0
  __syncthreads();
#pragma unroll
  for (int j = 0; j < 16; ++j) {  // T1 = L*T0
    prevpk[j] = curpk[j];
    curpk[j] = pack2(fa2[j]);
  }
  store_cur();
  __syncthreads();

  // ---- phases 1..3: T_{k+1} = 2*L*T_k - T_{k-1}
#pragma unroll
  for (int ph = 1; ph <= 3; ++ph) {
    gemm_acc(ph);
    gather();
    __syncthreads();
#pragma unroll
    for (int j = 0; j < 16; ++j) {
      u32 pv = prevpk[j];
      f32x2 t;
      t[0] = 2.f * fa2[j][0] - bflo(pv);
      t[1] = 2.f * fa2[j][1] - bfhi(pv);
      prevpk[j] = curpk[j];
      curpk[j] = pack2(t);
    }
    store_cur();
    __syncthreads();
  }

  // ---- phase 4
  gemm_acc(4);

  // ---- epilogue: C frag mapping col=lane&15, row=(lane>>4)*4+r  [m89]
#pragma unroll
  for (int n = 0; n < 2; ++n) {
    int fout = n * 16 + l15;
#pragma unroll
    for (int a = 0; a < 4; ++a) {
      int vrow0 = (w * 4 + a) * 16 + l4 * 4;
#pragma unroll
      for (int r = 0; r < 4; ++r) {
        out[((size_t)(b * FOUTC + fout) * V + (vrow0 + r)) * XYZ + xyz] = acc[a][n][r] + bsv[n];
      }
    }
  }
}

extern "C" void kernel_launch(void* const* d_in, const int* in_sizes, int n_in,
                              void* d_out, int out_size, void* d_ws, size_t ws_size,
                              hipStream_t stream) {
  const int*   lap_rows = (const int*)d_in[0];
  const int*   lap_cols = (const int*)d_in[1];
  const float* lap_vals = (const float*)d_in[2];
  const float* x        = (const float*)d_in[3];
  const float* weight   = (const float*)d_in[4];
  const float* bias     = (const float*)d_in[5];
  float* out = (float*)d_out;
  int nnz = in_sizes[0];

  char* ws = (char*)d_ws;
  const size_t XT_BYTES = (size_t)NB * XYZ * V * FINC * sizeof(u16);  // 50,331,648
  u16*  xT    = (u16*)ws;
  int2* epair = (int2*)(ws + XT_BYTES);
  int*  deg   = (int*)(ws + XT_BYTES + (size_t)V * MAXDEG * 8);

  hipLaunchKernelGGL(transpose_x, dim3(NB * V), dim3(512), 0, stream, x, xT);
  hipLaunchKernelGGL(build_ell, dim3(V), dim3(64), 0, stream,
                     lap_rows, lap_cols, lap_vals, nnz, epair, deg);
  hipLaunchKernelGGL(cheb_main, dim3(NB * XYZ), dim3(768), 0, stream,
                     xT, epair, deg, weight, bias, out);
}

// Round 3
// 343.799 us; speedup vs baseline: 1.1002x; 1.1002x over previous
//
#include <hip/hip_runtime.h>
#include <stdint.h>

#define V      768
#define FINC   32
#define FOUTC  32
#define XYZ    512
#define NB     2
#define ROWP   40      // padded LDS row stride in ushorts (80 B)
#define MAXDEG 32
#define CAP    20      // register-preloaded neighbors (zero-padded beyond deg)

typedef unsigned short u16;
typedef unsigned int   u32;
typedef short bf16x8 __attribute__((ext_vector_type(8)));
typedef float f32x4  __attribute__((ext_vector_type(4)));
typedef float f32x2  __attribute__((ext_vector_type(2)));

__device__ __forceinline__ u16 f2bf(float f) {
  u32 u = __float_as_uint(f);
  u32 r = u + 0x7fffu + ((u >> 16) & 1u);   // RNE
  return (u16)(r >> 16);
}
__device__ __forceinline__ float bflo(u32 w) { return __uint_as_float(w << 16); }
__device__ __forceinline__ float bfhi(u32 w) { return __uint_as_float(w & 0xffff0000u); }
__device__ __forceinline__ u32 cvtpk_bf16(float lo, float hi) {
  u32 r;
  asm("v_cvt_pk_bf16_f32 %0, %1, %2" : "=v"(r) : "v"(lo), "v"(hi));
  return r;
}

// ---------- kernel 1: x [B,Fin,V,XYZ] f32 -> xT [B,XYZ,V,Fin] bf16 ----------
__global__ __launch_bounds__(512) void transpose_x(const float* __restrict__ x,
                                                   u16* __restrict__ xT) {
  int g = blockIdx.x;            // b*V + v
  int b = g / V, v = g - b * V;
  int t = threadIdx.x;           // xyz
  float vals[FINC];
  const float* src = x + ((size_t)(b * FINC) * V + v) * XYZ + t;
#pragma unroll
  for (int f = 0; f < FINC; ++f) vals[f] = src[(size_t)f * V * XYZ];   // coalesced over t
  u32 pw[16];
#pragma unroll
  for (int p = 0; p < 16; ++p)
    pw[p] = (u32)f2bf(vals[2 * p]) | ((u32)f2bf(vals[2 * p + 1]) << 16);
  uint4* dst = (uint4*)(xT + ((size_t)(b * XYZ + t) * V + v) * FINC);  // 64B per thread
#pragma unroll
  for (int q = 0; q < 4; ++q)
    dst[q] = make_uint4(pw[4 * q], pw[4 * q + 1], pw[4 * q + 2], pw[4 * q + 3]);
}

// ---------- kernel 2: deterministic ELL build, interleaved (col,val), zero-padded ----------
__global__ __launch_bounds__(64) void build_ell(const int* __restrict__ rows,
                                                const int* __restrict__ cols,
                                                const float* __restrict__ vals,
                                                int nnz,
                                                int2* __restrict__ epair,
                                                int* __restrict__ deg) {
  int v = blockIdx.x;
  int lane = threadIdx.x;
  int cnt = 0;
  for (int base = 0; base < nnz; base += 64) {
    int i = base + lane;
    bool m = (i < nnz) && (rows[i] == v);
    unsigned long long mask = __ballot(m);
    if (m) {
      int pos = cnt + __popcll(mask & ((1ull << lane) - 1ull));
      if (pos < MAXDEG)
        epair[v * MAXDEG + pos] = make_int2(cols[i], __float_as_int(vals[i]));
    }
    cnt += __popcll(mask);
  }
  int d = cnt < MAXDEG ? cnt : MAXDEG;
  for (int p = d + lane; p < MAXDEG; p += 64)
    epair[v * MAXDEG + p] = make_int2(0, 0);   // val=0 -> padded iters are no-ops
  if (lane == 0) deg[v] = d;
}

// ---------- kernel 3: fused recursion + MFMA GEMM ----------
__global__ __launch_bounds__(768, 3) void cheb_main(
    const u16* __restrict__ xT, const int2* __restrict__ epair,
    const int* __restrict__ deg, const float* __restrict__ weight,
    const float* __restrict__ bias, float* __restrict__ out) {
  __shared__ __align__(16) u16  CUR[V * ROWP];      // 61440 B
  __shared__ __align__(16) uint4 WF[5][2][64];      // 10240 B weight fragments

  int g = blockIdx.x;
  // 32-xyz line-group per XCD: co-resident dirty lines = 3 MB < 4 MB L2
  int xcd = g & 7;
  int u = g >> 3;                 // 0..127
  int phase = u >> 5;             // 0..3
  int xyz = xcd * 32 + (u & 31) + (phase & 1) * 256;
  int b = phase >> 1;

  int tid = threadIdx.x;
  int lane = tid & 63;
  int w = tid >> 6;               // wave 0..11
  int l15 = lane & 15, l4 = lane >> 4;

  // ---- stage weight fragments to LDS (saves ~40 VGPRs)
  if (tid < 640) {
    int k = tid >> 7, n = (tid >> 6) & 1, ln = tid & 63;
    int a15 = ln & 15, a4 = ln >> 4;
    u32 pw[4];
#pragma unroll
    for (int p = 0; p < 4; ++p) {
      float w0 = weight[(size_t)(k * FINC + a4 * 8 + 2 * p) * FOUTC + n * 16 + a15];
      float w1 = weight[(size_t)(k * FINC + a4 * 8 + 2 * p + 1) * FOUTC + n * 16 + a15];
      pw[p] = (u32)f2bf(w0) | ((u32)f2bf(w1) << 16);
    }
    WF[k][n][ln] = make_uint4(pw[0], pw[1], pw[2], pw[3]);
  }
  float bsv[2] = {bias[l15], bias[16 + l15]};

  // ---- preload ELL (CAP entries) into registers; reused across all 4 gathers
  int dg = deg[tid];
  u32   eadr[CAP];
  float evl[CAP];
  {
    const int4* ep = (const int4*)(epair + (size_t)tid * MAXDEG);
#pragma unroll
    for (int h = 0; h < CAP / 2; ++h) {
      int4 q = ep[h];
      eadr[2 * h]     = (u32)q.x * (ROWP * 2);
      evl[2 * h]      = __int_as_float(q.y);
      eadr[2 * h + 1] = (u32)q.z * (ROWP * 2);
      evl[2 * h + 1]  = __int_as_float(q.w);
    }
  }

  // ---- load slice row tid into LDS, keep packed copy in regs
  u32 curpk[16], prevpk[16];
  {
    const uint4* src = (const uint4*)(xT + (size_t)(b * XYZ + xyz) * V * FINC) + tid * 4;
    uint4* dst = (uint4*)(CUR + tid * ROWP);
#pragma unroll
    for (int j = 0; j < 4; ++j) {
      uint4 q = src[j];
      dst[j] = q;
      curpk[4 * j] = q.x; curpk[4 * j + 1] = q.y;
      curpk[4 * j + 2] = q.z; curpk[4 * j + 3] = q.w;
    }
  }
  __syncthreads();

  f32x4 acc[4][2];
#pragma unroll
  for (int a = 0; a < 4; ++a)
#pragma unroll
    for (int n = 0; n < 2; ++n) acc[a][n] = (f32x4){0.f, 0.f, 0.f, 0.f};

  // out[v,fout] += sum_fin CUR[v,fin] * W[k,fin,fout]
  auto gemm_acc = [&](int k) {
    bf16x8 bn0 = *(const bf16x8*)&WF[k][0][lane];
    bf16x8 bn1 = *(const bf16x8*)&WF[k][1][lane];
#pragma unroll
    for (int a = 0; a < 4; ++a) {
      int row = (w * 4 + a) * 16 + l15;
      bf16x8 af = *(const bf16x8*)(CUR + row * ROWP + l4 * 8);
      acc[a][0] = __builtin_amdgcn_mfma_f32_16x16x32_bf16(af, bn0, acc[a][0], 0, 0, 0);
      acc[a][1] = __builtin_amdgcn_mfma_f32_16x16x32_bf16(af, bn1, acc[a][1], 0, 0, 0);
    }
  };

  // fa2 = (L * CUR)[tid, :] — fully unrolled, independent ds_reads, zero-padded
  f32x2 fa2[16];
  auto gather = [&]() {
#pragma unroll
    for (int j = 0; j < 16; ++j) fa2[j] = (f32x2){0.f, 0.f};
#pragma unroll
    for (int c = 0; c < CAP / 4; ++c) {
      if (!__any(dg > 4 * c)) break;          // wave-uniform early-out
#pragma unroll
      for (int q = 0; q < 4; ++q) {
        int e = 4 * c + q;
        f32x2 fv2 = {evl[e], evl[e]};
        const uint4* sp = (const uint4*)((const char*)CUR + eadr[e]);
#pragma unroll
        for (int j = 0; j < 4; ++j) {
          uint4 qq = sp[j];
          u32 wq[4] = {qq.x, qq.y, qq.z, qq.w};
#pragma unroll
          for (int p = 0; p < 4; ++p) {
            f32x2 s = {bflo(wq[p]), bfhi(wq[p])};
            fa2[j * 4 + p] += fv2 * s;
          }
        }
      }
    }
    if (__any(dg > CAP)) {                    // correctness fallback (≈never)
      for (int e = CAP; e < dg; ++e) {
        int2 pe = epair[(size_t)tid * MAXDEG + e];
        float fv = __int_as_float(pe.y);
        const uint4* sp = (const uint4*)(CUR + pe.x * ROWP);
#pragma unroll
        for (int j = 0; j < 4; ++j) {
          uint4 qq = sp[j];
          u32 wq[4] = {qq.x, qq.y, qq.z, qq.w};
#pragma unroll
          for (int p = 0; p < 4; ++p) {
            fa2[j * 4 + p][0] += fv * bflo(wq[p]);
            fa2[j * 4 + p][1] += fv * bfhi(wq[p]);
          }
        }
      }
    }
  };

  auto store_cur = [&]() {
    uint4* dp = (uint4*)(CUR + tid * ROWP);
#pragma unroll
    for (int j = 0; j < 4; ++j)
      dp[j] = make_uint4(curpk[4 * j], curpk[4 * j + 1], curpk[4 * j + 2], curpk[4 * j + 3]);
  };

  // ---- phase 0: T0 resident; T1 = L*T0
  gemm_acc(0);
  gather();
  __syncthreads();
#pragma unroll
  for (int j = 0; j < 16; ++j) {
    prevpk[j] = curpk[j];
    curpk[j] = cvtpk_bf16(fa2[j][0], fa2[j][1]);
  }
  store_cur();
  __syncthreads();

  // ---- phases 1..3: T_{k+1} = 2*L*T_k - T_{k-1}
#pragma unroll
  for (int ph = 1; ph <= 3; ++ph) {
    gemm_acc(ph);
    gather();
    __syncthreads();
#pragma unroll
    for (int j = 0; j < 16; ++j) {
      u32 pv = prevpk[j];
      float t0 = 2.f * fa2[j][0] - bflo(pv);
      float t1 = 2.f * fa2[j][1] - bfhi(pv);
      prevpk[j] = curpk[j];
      curpk[j] = cvtpk_bf16(t0, t1);
    }
    store_cur();
    __syncthreads();
  }

  // ---- phase 4
  gemm_acc(4);

  // ---- epilogue: C frag mapping col=lane&15, row=(lane>>4)*4+r  [m89]
#pragma unroll
  for (int n = 0; n < 2; ++n) {
    int fout = n * 16 + l15;
#pragma unroll
    for (int a = 0; a < 4; ++a) {
      int vrow0 = (w * 4 + a) * 16 + l4 * 4;
#pragma unroll
      for (int r = 0; r < 4; ++r) {
        out[((size_t)(b * FOUTC + fout) * V + (vrow0 + r)) * XYZ + xyz] = acc[a][n][r] + bsv[n];
      }
    }
  }
}

extern "C" void kernel_launch(void* const* d_in, const int* in_sizes, int n_in,
                              void* d_out, int out_size, void* d_ws, size_t ws_size,
                              hipStream_t stream) {
  const int*   lap_rows = (const int*)d_in[0];
  const int*   lap_cols = (const int*)d_in[1];
  const float* lap_vals = (const float*)d_in[2];
  const float* x        = (const float*)d_in[3];
  const float* weight   = (const float*)d_in[4];
  const float* bias     = (const float*)d_in[5];
  float* out = (float*)d_out;
  int nnz = in_sizes[0];

  char* ws = (char*)d_ws;
  const size_t XT_BYTES = (size_t)NB * XYZ * V * FINC * sizeof(u16);  // 50,331,648
  u16*  xT    = (u16*)ws;
  int2* epair = (int2*)(ws + XT_BYTES);
  int*  deg   = (int*)(ws + XT_BYTES + (size_t)V * MAXDEG * 8);

  hipLaunchKernelGGL(transpose_x, dim3(NB * V), dim3(512), 0, stream, x, xT);
  hipLaunchKernelGGL(build_ell, dim3(V), dim3(64), 0, stream,
                     lap_rows, lap_cols, lap_vals, nnz, epair, deg);
  hipLaunchKernelGGL(cheb_main, dim3(NB * XYZ), dim3(768), 0, stream,
                     xT, epair, deg, weight, bias, out);
}

// Round 4
// 317.627 us; speedup vs baseline: 1.1909x; 1.0824x over previous
//
#include <hip/hip_runtime.h>
#include <stdint.h>

#define V      768
#define FINC   32
#define FOUTC  32
#define XYZ    512
#define NB     2
#define ROWP   40      // padded LDS row stride in ushorts (80 B)
#define MAXDEG 32

typedef unsigned short u16;
typedef unsigned int   u32;
typedef short bf16x8 __attribute__((ext_vector_type(8)));
typedef float f32x4  __attribute__((ext_vector_type(4)));
typedef float f32x2  __attribute__((ext_vector_type(2)));

__device__ __forceinline__ u16 f2bf(float f) {
  u32 u = __float_as_uint(f);
  u32 r = u + 0x7fffu + ((u >> 16) & 1u);   // RNE
  return (u16)(r >> 16);
}
__device__ __forceinline__ float bflo(u32 w) { return __uint_as_float(w << 16); }
__device__ __forceinline__ float bfhi(u32 w) { return __uint_as_float(w & 0xffff0000u); }
__device__ __forceinline__ u32 cvtpk_bf16(float lo, float hi) {
  u32 r;
  asm("v_cvt_pk_bf16_f32 %0, %1, %2" : "=v"(r) : "v"(lo), "v"(hi));
  return r;
}

// ---------- kernel 1: deterministic ELL build, interleaved (col,val), zero-padded ----------
__global__ __launch_bounds__(64) void build_ell(const int* __restrict__ rows,
                                                const int* __restrict__ cols,
                                                const float* __restrict__ vals,
                                                int nnz,
                                                int2* __restrict__ epair,
                                                int* __restrict__ deg) {
  int v = blockIdx.x;
  int lane = threadIdx.x;
  int cnt = 0;
  for (int base = 0; base < nnz; base += 64) {
    int i = base + lane;
    bool m = (i < nnz) && (rows[i] == v);
    unsigned long long mask = __ballot(m);
    if (m) {
      int pos = cnt + __popcll(mask & ((1ull << lane) - 1ull));
      if (pos < MAXDEG)
        epair[v * MAXDEG + pos] = make_int2(cols[i], __float_as_int(vals[i]));
    }
    cnt += __popcll(mask);
  }
  int d = cnt < MAXDEG ? cnt : MAXDEG;
  for (int p = d + lane; p < MAXDEG; p += 64)
    epair[v * MAXDEG + p] = make_int2(0, 0);   // val=0 -> padded iters are no-ops
  if (lane == 0) deg[v] = d;
}

// ---------- kernel 2: degree sort (desc, tie by v) + SIMD-balanced group placement ----------
// wave->SIMD is w&3; static group->wave map balances per-SIMD trip sums.
__global__ __launch_bounds__(V) void sort_rows(const int2* __restrict__ epair,
                                               const int* __restrict__ deg,
                                               int2* __restrict__ epair2,
                                               int* __restrict__ perm,
                                               int* __restrict__ inv_g,
                                               int* __restrict__ wtrip) {
  __shared__ int sdeg[V];
  __shared__ u16 sinv[V];
  int v = threadIdx.x;
  int d = deg[v];
  sdeg[v] = d;
  __syncthreads();
  int r = 0;                       // sort rank (desc degree, tie v asc)
  for (int u = 0; u < V; ++u) {
    int du = sdeg[u];
    r += (du > d) || (du == d && u < v);
  }
  // group gr = r>>6 placed at wave GINV[gr]; nibble-packed GINV = {0,1,2,3,7,11,6,10,5,9,4,8}
  const unsigned long long GPK = 0x8495A6B73210ull;
  int w = (int)((GPK >> (4 * (r >> 6))) & 15ull);
  int p = w * 64 + (r & 63);       // final LDS/compute row
  perm[p] = v;
  inv_g[v] = p;
  sinv[v] = (u16)p;
  if ((r & 63) == 0) wtrip[w] = d; // rank-0 of group = its max degree
  __syncthreads();
  // rewrite ELL into permuted rows with precomputed LDS byte addresses
  for (int e = 0; e < MAXDEG; ++e) {
    int2 pe = epair[v * MAXDEG + e];
    int2 o = (e < d) ? make_int2((int)sinv[pe.x] * (ROWP * 2), pe.y) : make_int2(0, 0);
    epair2[p * MAXDEG + e] = o;
  }
}

// ---------- kernel 3: x [B,Fin,V,XYZ] f32 -> xT [B,XYZ,p,Fin] bf16 (row-permuted) ----------
__global__ __launch_bounds__(512) void transpose_x(const float* __restrict__ x,
                                                   const int* __restrict__ inv_g,
                                                   u16* __restrict__ xT) {
  int g = blockIdx.x;            // b*V + v
  int b = g / V, v = g - b * V;
  int pv = inv_g[v];             // block-uniform
  int t = threadIdx.x;           // xyz
  float vals[FINC];
  const float* src = x + ((size_t)(b * FINC) * V + v) * XYZ + t;
#pragma unroll
  for (int f = 0; f < FINC; ++f) vals[f] = src[(size_t)f * V * XYZ];   // coalesced over t
  u32 pw[16];
#pragma unroll
  for (int p = 0; p < 16; ++p)
    pw[p] = (u32)f2bf(vals[2 * p]) | ((u32)f2bf(vals[2 * p + 1]) << 16);
  uint4* dst = (uint4*)(xT + ((size_t)(b * XYZ + t) * V + pv) * FINC);
#pragma unroll
  for (int q = 0; q < 4; ++q)
    dst[q] = make_uint4(pw[4 * q], pw[4 * q + 1], pw[4 * q + 2], pw[4 * q + 3]);
}

// ---------- kernel 4: fused recursion + MFMA GEMM ----------
__global__ __launch_bounds__(768, 3) void cheb_main(
    const u16* __restrict__ xT, const int2* __restrict__ ep2,
    const int* __restrict__ perm, const int* __restrict__ wtrip,
    const float* __restrict__ weight, const float* __restrict__ bias,
    float* __restrict__ out) {
  __shared__ __align__(16) u16   CUR[V * ROWP];   // 61440 B
  __shared__ __align__(16) uint4 WF[5][2][64];    // 10240 B weight fragments
  __shared__ u16 PRM[V];                          // 1536 B
  __shared__ int WT[12];

  int g = blockIdx.x;
  // 32-xyz line-group per XCD
  int xcd = g & 7;
  int u = g >> 3;                 // 0..127
  int phase = u >> 5;             // 0..3
  int xyz = xcd * 32 + (u & 31) + (phase & 1) * 256;
  int b = phase >> 1;

  int tid = threadIdx.x;
  int lane = tid & 63;
  int w = tid >> 6;               // wave 0..11
  int l15 = lane & 15, l4 = lane >> 4;

  // ---- stage weight fragments to LDS
  if (tid < 640) {
    int k = tid >> 7, n = (tid >> 6) & 1, ln = tid & 63;
    int a15 = ln & 15, a4 = ln >> 4;
    u32 pw[4];
#pragma unroll
    for (int p = 0; p < 4; ++p) {
      float w0 = weight[(size_t)(k * FINC + a4 * 8 + 2 * p) * FOUTC + n * 16 + a15];
      float w1 = weight[(size_t)(k * FINC + a4 * 8 + 2 * p + 1) * FOUTC + n * 16 + a15];
      pw[p] = (u32)f2bf(w0) | ((u32)f2bf(w1) << 16);
    }
    WF[k][n][ln] = make_uint4(pw[0], pw[1], pw[2], pw[3]);
  }
  if (tid < 12) WT[tid] = wtrip[tid];
  PRM[tid] = (u16)perm[tid];
  float bsv[2] = {bias[l15], bias[16 + l15]};

  // ---- load permuted slice row tid into LDS, keep packed copy in regs
  u32 curpk[16], prevpk[16];
  {
    const uint4* src = (const uint4*)(xT + (size_t)(b * XYZ + xyz) * V * FINC) + tid * 4;
    uint4* dst = (uint4*)(CUR + tid * ROWP);
#pragma unroll
    for (int j = 0; j < 4; ++j) {
      uint4 q = src[j];
      dst[j] = q;
      curpk[4 * j] = q.x; curpk[4 * j + 1] = q.y;
      curpk[4 * j + 2] = q.z; curpk[4 * j + 3] = q.w;
    }
  }
  __syncthreads();

  int trip = __builtin_amdgcn_readfirstlane(WT[w]);   // wave-uniform scalar
  const int2* pp = ep2 + (size_t)tid * MAXDEG;

  f32x4 acc[4][2];
#pragma unroll
  for (int a = 0; a < 4; ++a)
#pragma unroll
    for (int n = 0; n < 2; ++n) acc[a][n] = (f32x4){0.f, 0.f, 0.f, 0.f};

  auto gemm_acc = [&](int k) {
    bf16x8 bn0 = *(const bf16x8*)&WF[k][0][lane];
    bf16x8 bn1 = *(const bf16x8*)&WF[k][1][lane];
#pragma unroll
    for (int a = 0; a < 4; ++a) {
      int row = (w * 4 + a) * 16 + l15;
      bf16x8 af = *(const bf16x8*)(CUR + row * ROWP + l4 * 8);
      acc[a][0] = __builtin_amdgcn_mfma_f32_16x16x32_bf16(af, bn0, acc[a][0], 0, 0, 0);
      acc[a][1] = __builtin_amdgcn_mfma_f32_16x16x32_bf16(af, bn1, acc[a][1], 0, 0, 0);
    }
  };

  // fa2 = (L * CUR)[tid, :] — SGPR trip count, one-ahead ELL prefetch
  f32x2 fa2[16];
  auto gather = [&]() {
#pragma unroll
    for (int j = 0; j < 16; ++j) fa2[j] = (f32x2){0.f, 0.f};
    int2 pe = pp[0];
    for (int e = 0; e < trip; ++e) {
      int2 nx = pp[e + 1];                     // prefetch (pad alloc'd past end)
      float fv = __int_as_float(pe.y);
      f32x2 fv2 = {fv, fv};
      const uint4* sp = (const uint4*)((const char*)CUR + (u32)pe.x);
      uint4 qa = sp[0], qb = sp[1], qc = sp[2], qd = sp[3];
      u32 wq[16] = {qa.x, qa.y, qa.z, qa.w, qb.x, qb.y, qb.z, qb.w,
                    qc.x, qc.y, qc.z, qc.w, qd.x, qd.y, qd.z, qd.w};
#pragma unroll
      for (int p = 0; p < 16; ++p) {
        f32x2 s = {bflo(wq[p]), bfhi(wq[p])};
        fa2[p] += fv2 * s;
      }
      pe = nx;
    }
  };

  auto store_cur = [&]() {
    uint4* dp = (uint4*)(CUR + tid * ROWP);
#pragma unroll
    for (int j = 0; j < 4; ++j)
      dp[j] = make_uint4(curpk[4 * j], curpk[4 * j + 1], curpk[4 * j + 2], curpk[4 * j + 3]);
  };

  // ---- phase 0: T0 resident; T1 = L*T0
  gemm_acc(0);
  gather();
  __syncthreads();
#pragma unroll
  for (int j = 0; j < 16; ++j) {
    prevpk[j] = curpk[j];
    curpk[j] = cvtpk_bf16(fa2[j][0], fa2[j][1]);
  }
  store_cur();
  __syncthreads();

  // ---- phases 1..3: T_{k+1} = 2*L*T_k - T_{k-1}
#pragma unroll
  for (int ph = 1; ph <= 3; ++ph) {
    gemm_acc(ph);
    gather();
    __syncthreads();
#pragma unroll
    for (int j = 0; j < 16; ++j) {
      u32 pv = prevpk[j];
      float t0 = 2.f * fa2[j][0] - bflo(pv);
      float t1 = 2.f * fa2[j][1] - bfhi(pv);
      prevpk[j] = curpk[j];
      curpk[j] = cvtpk_bf16(t0, t1);
    }
    store_cur();
    __syncthreads();
  }

  // ---- phase 4
  gemm_acc(4);

  // ---- epilogue: C frag mapping col=lane&15, row=(lane>>4)*4+r; un-permute rows via PRM
#pragma unroll
  for (int n = 0; n < 2; ++n) {
    int fout = n * 16 + l15;
#pragma unroll
    for (int a = 0; a < 4; ++a) {
      int vrow0 = (w * 4 + a) * 16 + l4 * 4;
#pragma unroll
      for (int r = 0; r < 4; ++r) {
        int vr = PRM[vrow0 + r];
        out[((size_t)(b * FOUTC + fout) * V + vr) * XYZ + xyz] = acc[a][n][r] + bsv[n];
      }
    }
  }
}

extern "C" void kernel_launch(void* const* d_in, const int* in_sizes, int n_in,
                              void* d_out, int out_size, void* d_ws, size_t ws_size,
                              hipStream_t stream) {
  const int*   lap_rows = (const int*)d_in[0];
  const int*   lap_cols = (const int*)d_in[1];
  const float* lap_vals = (const float*)d_in[2];
  const float* x        = (const float*)d_in[3];
  const float* weight   = (const float*)d_in[4];
  const float* bias     = (const float*)d_in[5];
  float* out = (float*)d_out;
  int nnz = in_sizes[0];

  char* ws = (char*)d_ws;
  const size_t XT_BYTES = (size_t)NB * XYZ * V * FINC * sizeof(u16);  // 50,331,648
  const size_t EP_BYTES = (size_t)V * MAXDEG * 8;                     // 196,608
  u16*  xT     = (u16*)ws;
  int2* epair  = (int2*)(ws + XT_BYTES);
  int2* epair2 = (int2*)(ws + XT_BYTES + EP_BYTES);                   // +64B pad after
  int*  deg    = (int*)(ws + XT_BYTES + 2 * EP_BYTES + 64);
  int*  perm   = (int*)(ws + XT_BYTES + 2 * EP_BYTES + 64 + 3072);
  int*  inv_g  = (int*)(ws + XT_BYTES + 2 * EP_BYTES + 64 + 6144);
  int*  wtrip  = (int*)(ws + XT_BYTES + 2 * EP_BYTES + 64 + 9216);

  hipLaunchKernelGGL(build_ell, dim3(V), dim3(64), 0, stream,
                     lap_rows, lap_cols, lap_vals, nnz, epair, deg);
  hipLaunchKernelGGL(sort_rows, dim3(1), dim3(V), 0, stream,
                     epair, deg, epair2, perm, inv_g, wtrip);
  hipLaunchKernelGGL(transpose_x, dim3(NB * V), dim3(512), 0, stream, x, inv_g, xT);
  hipLaunchKernelGGL(cheb_main, dim3(NB * XYZ), dim3(768), 0, stream,
                     xT, epair2, perm, wtrip, weight, bias, out);
}

// Round 5
// 220.296 us; speedup vs baseline: 1.7170x; 1.4418x over previous
//
#include <hip/hip_runtime.h>
#include <stdint.h>

#define V      768
#define FINC   32
#define FOUTC  32
#define XYZ    512
#define NB     2
#define ROWP   40      // padded LDS row stride in ushorts (80 B)
#define MAXDEG 32
#define EROWS  (MAXDEG + 2)   // transposed-ELL rows incl. prefetch pad

typedef unsigned short u16;
typedef unsigned int   u32;
typedef short bf16x8 __attribute__((ext_vector_type(8)));
typedef float f32x4  __attribute__((ext_vector_type(4)));
typedef float f32x2  __attribute__((ext_vector_type(2)));

__device__ __forceinline__ u16 f2bf(float f) {
  u32 u = __float_as_uint(f);
  u32 r = u + 0x7fffu + ((u >> 16) & 1u);   // RNE
  return (u16)(r >> 16);
}
__device__ __forceinline__ float bflo(u32 w) { return __uint_as_float(w << 16); }
__device__ __forceinline__ float bfhi(u32 w) { return __uint_as_float(w & 0xffff0000u); }
__device__ __forceinline__ u32 cvtpk_bf16(float lo, float hi) {
  u32 r;
  asm("v_cvt_pk_bf16_f32 %0, %1, %2" : "=v"(r) : "v"(lo), "v"(hi));
  return r;
}

// ---------- kernel 1: deterministic ELL build, interleaved (col,val), zero-padded ----------
__global__ __launch_bounds__(64) void build_ell(const int* __restrict__ rows,
                                                const int* __restrict__ cols,
                                                const float* __restrict__ vals,
                                                int nnz,
                                                int2* __restrict__ epair,
                                                int* __restrict__ deg) {
  int v = blockIdx.x;
  int lane = threadIdx.x;
  int cnt = 0;
  for (int base = 0; base < nnz; base += 64) {
    int i = base + lane;
    bool m = (i < nnz) && (rows[i] == v);
    unsigned long long mask = __ballot(m);
    if (m) {
      int pos = cnt + __popcll(mask & ((1ull << lane) - 1ull));
      if (pos < MAXDEG)
        epair[v * MAXDEG + pos] = make_int2(cols[i], __float_as_int(vals[i]));
    }
    cnt += __popcll(mask);
  }
  int d = cnt < MAXDEG ? cnt : MAXDEG;
  for (int p = d + lane; p < MAXDEG; p += 64)
    epair[v * MAXDEG + p] = make_int2(0, 0);
  if (lane == 0) deg[v] = d;
}

// ---------- kernel 2: degree sort + SIMD-balanced placement + TRANSPOSED ELL ----------
__global__ __launch_bounds__(V) void sort_rows(const int2* __restrict__ epair,
                                               const int* __restrict__ deg,
                                               int2* __restrict__ ep3,     // [EROWS][V]
                                               int* __restrict__ perm,
                                               int* __restrict__ inv_g,
                                               int* __restrict__ wtrip) {
  __shared__ int sdeg[V];
  __shared__ u16 sinv[V];
  int v = threadIdx.x;
  int d = deg[v];
  sdeg[v] = d;
  __syncthreads();
  int r = 0;                       // rank (desc degree, tie v asc)
  for (int u = 0; u < V; ++u) {
    int du = sdeg[u];
    r += (du > d) || (du == d && u < v);
  }
  // group gr=r>>6 -> wave GINV[gr]; nibble-packed GINV = {0,1,2,3,7,11,6,10,5,9,4,8}
  const unsigned long long GPK = 0x8495A6B73210ull;
  int w = (int)((GPK >> (4 * (r >> 6))) & 15ull);
  int p = w * 64 + (r & 63);
  perm[p] = v;
  inv_g[v] = p;
  sinv[v] = (u16)p;
  if ((r & 63) == 0) wtrip[w] = d;
  __syncthreads();
  // transposed ELL with precomputed LDS byte addresses; zero pad rows (incl. prefetch pad)
  for (int e = 0; e < EROWS; ++e) {
    int2 o = make_int2(0, 0);
    if (e < d) {
      int2 pe = epair[v * MAXDEG + e];
      o = make_int2((int)sinv[pe.x] * (ROWP * 2), pe.y);
    }
    ep3[e * V + p] = o;
  }
}

// ---------- kernel 3: x [B,Fin,V,XYZ] f32 -> xT [B,XYZ,p,Fin] bf16 (row-permuted) ----------
__global__ __launch_bounds__(512) void transpose_x(const float* __restrict__ x,
                                                   const int* __restrict__ inv_g,
                                                   u16* __restrict__ xT) {
  int g = blockIdx.x;            // b*V + v
  int b = g / V, v = g - b * V;
  int pv = inv_g[v];
  int t = threadIdx.x;           // xyz
  float vals[FINC];
  const float* src = x + ((size_t)(b * FINC) * V + v) * XYZ + t;
#pragma unroll
  for (int f = 0; f < FINC; ++f) vals[f] = src[(size_t)f * V * XYZ];
  u32 pw[16];
#pragma unroll
  for (int p = 0; p < 16; ++p)
    pw[p] = (u32)f2bf(vals[2 * p]) | ((u32)f2bf(vals[2 * p + 1]) << 16);
  uint4* dst = (uint4*)(xT + ((size_t)(b * XYZ + t) * V + pv) * FINC);
#pragma unroll
  for (int q = 0; q < 4; ++q)
    dst[q] = make_uint4(pw[4 * q], pw[4 * q + 1], pw[4 * q + 2], pw[4 * q + 3]);
}

// ---------- kernel 4: fused recursion + MFMA GEMM; writes bf16 stage (aliases xT) ----------
__global__ __launch_bounds__(768, 3) void cheb_main(
    const u16* __restrict__ xT, const int2* __restrict__ ep3,
    const int* __restrict__ perm, const int* __restrict__ wtrip,
    const float* __restrict__ weight, const float* __restrict__ bias,
    u32* __restrict__ stage) {
  __shared__ __align__(16) u16   CUR[V * ROWP];   // 61440 B
  __shared__ __align__(16) uint4 WF[5][2][64];    // 10240 B
  __shared__ u16 PRM[V];
  __shared__ int WT[12];

  int g = blockIdx.x;
  int xcd = g & 7;
  int u = g >> 3;
  int phase = u >> 5;
  int xyz = xcd * 32 + (u & 31) + (phase & 1) * 256;
  int b = phase >> 1;
  int slice = b * XYZ + xyz;

  int tid = threadIdx.x;
  int lane = tid & 63;
  int w = tid >> 6;
  int l15 = lane & 15, l4 = lane >> 4;

  if (tid < 640) {
    int k = tid >> 7, n = (tid >> 6) & 1, ln = tid & 63;
    int a15 = ln & 15, a4 = ln >> 4;
    u32 pw[4];
#pragma unroll
    for (int p = 0; p < 4; ++p) {
      float w0 = weight[(size_t)(k * FINC + a4 * 8 + 2 * p) * FOUTC + n * 16 + a15];
      float w1 = weight[(size_t)(k * FINC + a4 * 8 + 2 * p + 1) * FOUTC + n * 16 + a15];
      pw[p] = (u32)f2bf(w0) | ((u32)f2bf(w1) << 16);
    }
    WF[k][n][ln] = make_uint4(pw[0], pw[1], pw[2], pw[3]);
  }
  if (tid < 12) WT[tid] = wtrip[tid];
  PRM[tid] = (u16)perm[tid];
  float bsv[2] = {bias[l15], bias[16 + l15]};

  // ---- load permuted slice row tid into LDS, keep packed copy in regs
  u32 curpk[16], prevpk[16];
  {
    const uint4* src = (const uint4*)(xT + (size_t)slice * V * FINC) + tid * 4;
    uint4* dst = (uint4*)(CUR + tid * ROWP);
#pragma unroll
    for (int j = 0; j < 4; ++j) {
      uint4 q = src[j];
      dst[j] = q;
      curpk[4 * j] = q.x; curpk[4 * j + 1] = q.y;
      curpk[4 * j + 2] = q.z; curpk[4 * j + 3] = q.w;
    }
  }
  __syncthreads();   // also orders all xT reads before the aliased stage writes at the end

  int trip = __builtin_amdgcn_readfirstlane(WT[w]);
  const int2* pp = ep3 + tid;

  f32x4 acc[4][2];
#pragma unroll
  for (int a = 0; a < 4; ++a)
#pragma unroll
    for (int n = 0; n < 2; ++n) acc[a][n] = (f32x4){0.f, 0.f, 0.f, 0.f};

  auto gemm_acc = [&](int k) {
    bf16x8 bn0 = *(const bf16x8*)&WF[k][0][lane];
    bf16x8 bn1 = *(const bf16x8*)&WF[k][1][lane];
#pragma unroll
    for (int a = 0; a < 4; ++a) {
      int row = (w * 4 + a) * 16 + l15;
      bf16x8 af = *(const bf16x8*)(CUR + row * ROWP + l4 * 8);
      acc[a][0] = __builtin_amdgcn_mfma_f32_16x16x32_bf16(af, bn0, acc[a][0], 0, 0, 0);
      acc[a][1] = __builtin_amdgcn_mfma_f32_16x16x32_bf16(af, bn1, acc[a][1], 0, 0, 0);
    }
  };

  // fa2 = (L * CUR)[tid,:] — SGPR trip, coalesced transposed-ELL, 2-deep prefetch
  f32x2 fa2[16];
  auto gather = [&]() {
#pragma unroll
    for (int j = 0; j < 16; ++j) fa2[j] = (f32x2){0.f, 0.f};
    int2 pe0 = pp[0];
    int2 pe1 = pp[V];
    for (int e = 0; e < trip; ++e) {
      int2 nx = pp[(e + 2) * V];
      float fv = __int_as_float(pe0.y);
      f32x2 fv2 = {fv, fv};
      const uint4* sp = (const uint4*)((const char*)CUR + (u32)pe0.x);
      uint4 qa = sp[0], qb = sp[1], qc = sp[2], qd = sp[3];
      u32 wq[16] = {qa.x, qa.y, qa.z, qa.w, qb.x, qb.y, qb.z, qb.w,
                    qc.x, qc.y, qc.z, qc.w, qd.x, qd.y, qd.z, qd.w};
#pragma unroll
      for (int p = 0; p < 16; ++p) {
        f32x2 s = {bflo(wq[p]), bfhi(wq[p])};
        fa2[p] += fv2 * s;
      }
      pe0 = pe1; pe1 = nx;
    }
  };

  auto store_cur = [&]() {
    uint4* dp = (uint4*)(CUR + tid * ROWP);
#pragma unroll
    for (int j = 0; j < 4; ++j)
      dp[j] = make_uint4(curpk[4 * j], curpk[4 * j + 1], curpk[4 * j + 2], curpk[4 * j + 3]);
  };

  // ---- phase 0: T0 resident; T1 = L*T0
  gemm_acc(0);
  gather();
  __syncthreads();
#pragma unroll
  for (int j = 0; j < 16; ++j) {
    prevpk[j] = curpk[j];
    curpk[j] = cvtpk_bf16(fa2[j][0], fa2[j][1]);
  }
  store_cur();
  __syncthreads();

  // ---- phases 1..3: T_{k+1} = 2*L*T_k - T_{k-1}
#pragma unroll
  for (int ph = 1; ph <= 3; ++ph) {
    gemm_acc(ph);
    gather();
    __syncthreads();
#pragma unroll
    for (int j = 0; j < 16; ++j) {
      u32 pv = prevpk[j];
      float t0 = 2.f * fa2[j][0] - bflo(pv);
      float t1 = 2.f * fa2[j][1] - bfhi(pv);
      prevpk[j] = curpk[j];
      curpk[j] = cvtpk_bf16(t0, t1);
    }
    store_cur();
    __syncthreads();
  }

  // ---- phase 4
  gemm_acc(4);

  // ---- epilogue: pack (fout, fout+16) per lane -> bf16 stage[slice][v][l15]
  u32* stg = stage + (size_t)slice * (V * 16);
#pragma unroll
  for (int a = 0; a < 4; ++a) {
#pragma unroll
    for (int r = 0; r < 4; ++r) {
      int vr = PRM[(w * 4 + a) * 16 + l4 * 4 + r];
      u32 pk = cvtpk_bf16(acc[a][0][r] + bsv[0], acc[a][1][r] + bsv[1]);
      stg[vr * 16 + l15] = pk;
    }
  }
}

// ---------- kernel 5: stage [b][xyz][v][f2] bf16 -> out [b][fout][v][xyz] f32 ----------
#define TO_VT  12
#define TO_PAD 193
__global__ __launch_bounds__(512) void transpose_out(const u32* __restrict__ stage,
                                                     float* __restrict__ out) {
  __shared__ u32 T[64 * TO_PAD];   // 49.4 KB
  int g = blockIdx.x;              // b(2) x vt(64) x xt(8)
  int b = g >> 9, vt = (g >> 3) & 63, xt = g & 7;
  int v0 = vt * TO_VT;
  int xyz0 = xt * 64;
  int t = threadIdx.x;
  int j = t >> 3, s = t & 7;       // xyz-within-tile, sub-reader
  const u32* src = stage + (size_t)(b * XYZ + xyz0 + j) * (V * 16) + v0 * 16 + s * 24;
#pragma unroll
  for (int i = 0; i < 24; i += 4) {
    uint4 q = *(const uint4*)(src + i);
    int w0 = s * 24 + i;
    T[j * TO_PAD + w0]     = q.x;
    T[j * TO_PAD + w0 + 1] = q.y;
    T[j * TO_PAD + w0 + 2] = q.z;
    T[j * TO_PAD + w0 + 3] = q.w;
  }
  __syncthreads();
  int wv = t >> 6, lane = t & 63;  // wave, lane=xyz
#pragma unroll
  for (int i = 0; i < 48; ++i) {
    int fout = wv * 4 + i / 12;    // wv*48 divisible by 12 -> compile-time split
    int vv = i % 12;
    u32 pk = T[lane * TO_PAD + vv * 16 + (fout & 15)];
    float val = (fout < 16) ? bflo(pk) : bfhi(pk);
    out[((size_t)(b * FOUTC + fout) * V + v0 + vv) * XYZ + xyz0 + lane] = val;
  }
}

extern "C" void kernel_launch(void* const* d_in, const int* in_sizes, int n_in,
                              void* d_out, int out_size, void* d_ws, size_t ws_size,
                              hipStream_t stream) {
  const int*   lap_rows = (const int*)d_in[0];
  const int*   lap_cols = (const int*)d_in[1];
  const float* lap_vals = (const float*)d_in[2];
  const float* x        = (const float*)d_in[3];
  const float* weight   = (const float*)d_in[4];
  const float* bias     = (const float*)d_in[5];
  float* out = (float*)d_out;
  int nnz = in_sizes[0];

  char* ws = (char*)d_ws;
  const size_t XT_BYTES = (size_t)NB * XYZ * V * FINC * sizeof(u16);  // 50,331,648
  const size_t EP_BYTES = (size_t)V * MAXDEG * 8;                     // 196,608
  const size_t E3_BYTES = (size_t)EROWS * V * 8;                      // 208,896
  u16*  xT    = (u16*)ws;                // aliased: bf16 stage [b][xyz][v][f2]
  u32*  stg   = (u32*)ws;
  int2* epair = (int2*)(ws + XT_BYTES);
  int2* ep3   = (int2*)(ws + XT_BYTES + EP_BYTES);
  int*  deg   = (int*)(ws + XT_BYTES + EP_BYTES + E3_BYTES);
  int*  perm  = (int*)(ws + XT_BYTES + EP_BYTES + E3_BYTES + 3072);
  int*  inv_g = (int*)(ws + XT_BYTES + EP_BYTES + E3_BYTES + 6144);
  int*  wtrip = (int*)(ws + XT_BYTES + EP_BYTES + E3_BYTES + 9216);

  hipLaunchKernelGGL(build_ell, dim3(V), dim3(64), 0, stream,
                     lap_rows, lap_cols, lap_vals, nnz, epair, deg);
  hipLaunchKernelGGL(sort_rows, dim3(1), dim3(V), 0, stream,
                     epair, deg, ep3, perm, inv_g, wtrip);
  hipLaunchKernelGGL(transpose_x, dim3(NB * V), dim3(512), 0, stream, x, inv_g, xT);
  hipLaunchKernelGGL(cheb_main, dim3(NB * XYZ), dim3(768), 0, stream,
                     xT, ep3, perm, wtrip, weight, bias, stg);
  hipLaunchKernelGGL(transpose_out, dim3(NB * 64 * 8), dim3(512), 0, stream,
                     stg, out);
}